// Round 1
// baseline (7624.687 us; speedup 1.0000x reference)
//
#include <hip/hip_runtime.h>
#include <math.h>

#define HID 256
#define MOTIF 640
#define PEAK 1000
#define NPEAKS 128   // B * NUM_PEAKS
#define DEPTHN 7
#define PROFK 75
#define FINLEN 492
#define PROFLEN 418

// ---------------------------------------------------------------------------
// Projection: h0[n][c][t] = sum_m W[c][m] * x[n*1000+t][m] + b[c]
// grid (t_tiles=16, c_tiles=4, n=128), block 256
// ---------------------------------------------------------------------------
__global__ __launch_bounds__(256) void proj_kernel(
    const float* __restrict__ x, const float* __restrict__ wproj,
    const float* __restrict__ bproj, float* __restrict__ out)
{
    __shared__ __attribute__((aligned(16))) float xs[64][68];
    __shared__ __attribute__((aligned(16))) float ws[64][68];
    const int tid = threadIdx.x;
    const int t0 = blockIdx.x * 64;
    const int c0 = blockIdx.y * 64;
    const int n  = blockIdx.z;
    const int tt = tid & 15, tc = tid >> 4;
    float acc[4][4] = {};

    for (int m0 = 0; m0 < MOTIF; m0 += 64) {
        #pragma unroll
        for (int q = 0; q < 4; ++q) {
            int idx  = tid * 4 + q;       // 0..1023 float4 slots
            int row  = idx >> 4;
            int col4 = idx & 15;
            int trow = t0 + row; if (trow > PEAK - 1) trow = PEAK - 1;
            float4 xv = *(const float4*)(x + ((size_t)(n * PEAK + trow)) * MOTIF + m0 + col4 * 4);
            *(float4*)&xs[row][col4 * 4] = xv;
            float4 wv = *(const float4*)(wproj + (size_t)(c0 + row) * MOTIF + m0 + col4 * 4);
            *(float4*)&ws[row][col4 * 4] = wv;
        }
        __syncthreads();
        #pragma unroll
        for (int m4 = 0; m4 < 16; ++m4) {
            float4 wv[4], xv[4];
            #pragma unroll
            for (int i = 0; i < 4; ++i) wv[i] = *(const float4*)&ws[tc * 4 + i][m4 * 4];
            #pragma unroll
            for (int j = 0; j < 4; ++j) xv[j] = *(const float4*)&xs[tt * 4 + j][m4 * 4];
            #pragma unroll
            for (int i = 0; i < 4; ++i)
                #pragma unroll
                for (int j = 0; j < 4; ++j)
                    acc[i][j] += wv[i].x * xv[j].x + wv[i].y * xv[j].y
                               + wv[i].z * xv[j].z + wv[i].w * xv[j].w;
        }
        __syncthreads();
    }
    #pragma unroll
    for (int i = 0; i < 4; ++i) {
        int c = c0 + tc * 4 + i;
        float b = bproj[c];
        int t = t0 + tt * 4;
        if (t + 3 < PEAK) {
            float4 v = make_float4(acc[i][0] + b, acc[i][1] + b, acc[i][2] + b, acc[i][3] + b);
            *(float4*)(out + ((size_t)n * HID + c) * PEAK + t) = v;
        }
    }
}

// ---------------------------------------------------------------------------
// Dilated conv layer:
// out[n][c][t] = relu( sum_{ci,k} W[c][ci][k] * in[n][ci][t+k*dil] + bias[c] )
//               + in[n][c][t+dil]
// grid (t_tiles, 4, 128), block 256
// ---------------------------------------------------------------------------
__global__ __launch_bounds__(256) void dconv_kernel(
    const float* __restrict__ in, int in_len,
    float* __restrict__ out, int out_len, int dil,
    const float* __restrict__ w, const float* __restrict__ bias)
{
    __shared__ __attribute__((aligned(16))) float ws[3][32][68];  // [k][ci][c]
    __shared__ __attribute__((aligned(16))) float is[3][32][68];  // [k][ci][t]
    const int tid = threadIdx.x;
    const int t0 = blockIdx.x * 64;
    const int c0 = blockIdx.y * 64;
    const int n  = blockIdx.z;
    const float* inN = in + (size_t)n * HID * in_len;
    const int tt = tid & 15, tc = tid >> 4;
    float acc[4][4] = {};

    for (int ci0 = 0; ci0 < HID; ci0 += 32) {
        // weights: 64c x 32ci x 3k = 6144 floats, 24 per thread
        #pragma unroll
        for (int q = 0; q < 24; ++q) {
            int lin = q * 256 + tid;
            int c = lin / 96;         // 96 = 32*3
            int r = lin - c * 96;
            int ci = r / 3, k = r - ci * 3;
            ws[k][ci][c] = w[(size_t)(c0 + c) * (HID * 3) + (size_t)(ci0 + ci) * 3 + k];
        }
        // input slices: 3k x 32ci x 64t
        #pragma unroll
        for (int q = 0; q < 24; ++q) {
            int lin = q * 256 + tid;
            int t  = lin & 63;
            int ci = (lin >> 6) & 31;
            int k  = lin >> 11;
            int ti = t0 + t + k * dil;
            if (ti > in_len - 1) ti = in_len - 1;   // guarded tiles only
            is[k][ci][t] = inN[(size_t)(ci0 + ci) * in_len + ti];
        }
        __syncthreads();
        for (int ci = 0; ci < 32; ++ci) {
            #pragma unroll
            for (int k = 0; k < 3; ++k) {
                float4 wv = *(const float4*)&ws[k][ci][tc * 4];
                float4 iv = *(const float4*)&is[k][ci][tt * 4];
                acc[0][0] += wv.x * iv.x; acc[0][1] += wv.x * iv.y;
                acc[0][2] += wv.x * iv.z; acc[0][3] += wv.x * iv.w;
                acc[1][0] += wv.y * iv.x; acc[1][1] += wv.y * iv.y;
                acc[1][2] += wv.y * iv.z; acc[1][3] += wv.y * iv.w;
                acc[2][0] += wv.z * iv.x; acc[2][1] += wv.z * iv.y;
                acc[2][2] += wv.z * iv.z; acc[2][3] += wv.z * iv.w;
                acc[3][0] += wv.w * iv.x; acc[3][1] += wv.w * iv.y;
                acc[3][2] += wv.w * iv.z; acc[3][3] += wv.w * iv.w;
            }
        }
        __syncthreads();
    }
    #pragma unroll
    for (int i = 0; i < 4; ++i) {
        int c = c0 + tc * 4 + i;
        float b = bias[c];
        #pragma unroll
        for (int j = 0; j < 4; ++j) {
            int t = t0 + tt * 4 + j;
            if (t < out_len) {
                float v = acc[i][j] + b;
                v = fmaxf(v, 0.f);
                v += inN[(size_t)c * in_len + t + dil];   // residual (crop = dil)
                out[((size_t)n * HID + c) * out_len + t] = v;
            }
        }
    }
}

// ---------------------------------------------------------------------------
// atpm: out[n] = softplus( sum_c (mean_t h[n][c][t]) * w_atpm[c] + b_atpm )
// grid 128, block 256 (thread = channel)
// ---------------------------------------------------------------------------
__global__ __launch_bounds__(256) void atpm_kernel(
    const float* __restrict__ h,
    const float* __restrict__ watpm, const float* __restrict__ batpm,
    float* __restrict__ outAtpm)
{
    const int n = blockIdx.x;
    const int c = threadIdx.x;
    const float* row = h + ((size_t)n * HID + c) * FINLEN;
    float s = 0.f;
    for (int t = 0; t < FINLEN; t += 4) {
        float4 v = *(const float4*)(row + t);
        s += v.x + v.y + v.z + v.w;
    }
    float v = (s / (float)FINLEN) * watpm[c];
    __shared__ float red[4];
    #pragma unroll
    for (int off = 32; off > 0; off >>= 1) v += __shfl_down(v, off, 64);
    if ((threadIdx.x & 63) == 0) red[threadIdx.x >> 6] = v;
    __syncthreads();
    if (threadIdx.x == 0) {
        float tot = red[0] + red[1] + red[2] + red[3] + batpm[0];
        outAtpm[n] = fmaxf(tot, 0.f) + log1pf(expf(-fabsf(tot)));
    }
}

// ---------------------------------------------------------------------------
// profile: out[n][t] = softplus( sum_{ci,k} w_prof[ci][k]*h[n][ci][t+k] + b )
// grid (2, 128), block 256 (thread = t position)
// ---------------------------------------------------------------------------
__global__ __launch_bounds__(256) void prof_kernel(
    const float* __restrict__ h,
    const float* __restrict__ wprof, const float* __restrict__ bprof,
    float* __restrict__ outProf)
{
    __shared__ float hs[16][FINLEN];   // 31.5 KB
    __shared__ float wsh[16][PROFK + 1];
    const int n = blockIdx.y;
    const int t = blockIdx.x * 256 + threadIdx.x;
    const float* hN = h + (size_t)n * HID * FINLEN;
    float acc = 0.f;
    for (int ci0 = 0; ci0 < HID; ci0 += 16) {
        for (int q = threadIdx.x; q < 16 * FINLEN; q += 256) {
            int ci = q / FINLEN, t2 = q - ci * FINLEN;
            hs[ci][t2] = hN[(size_t)(ci0 + ci) * FINLEN + t2];
        }
        for (int q = threadIdx.x; q < 16 * PROFK; q += 256) {
            int ci = q / PROFK, k = q - ci * PROFK;
            wsh[ci][k] = wprof[(ci0 + ci) * PROFK + k];
        }
        __syncthreads();
        if (t < PROFLEN) {
            for (int ci = 0; ci < 16; ++ci)
                for (int k = 0; k < PROFK; ++k)
                    acc += wsh[ci][k] * hs[ci][t + k];
        }
        __syncthreads();
    }
    if (t < PROFLEN) {
        float v = acc + bprof[0];
        outProf[(size_t)n * PROFLEN + t] = fmaxf(v, 0.f) + log1pf(expf(-fabsf(v)));
    }
}

// ---------------------------------------------------------------------------
extern "C" void kernel_launch(void* const* d_in, const int* in_sizes, int n_in,
                              void* d_out, int out_size, void* d_ws, size_t ws_size,
                              hipStream_t stream) {
    const float* x     = (const float*)d_in[0];
    // d_in[1] peak_split, d_in[2] n_peaks, d_in[3] max_n_peaks (fast path hardcoded)
    const float* wproj = (const float*)d_in[4];
    const float* bproj = (const float*)d_in[5];
    const float* wdil  = (const float*)d_in[6];
    const float* bdil  = (const float*)d_in[7];
    const float* wprof = (const float*)d_in[8];
    const float* bprof = (const float*)d_in[9];
    const float* watpm = (const float*)d_in[10];
    const float* batpm = (const float*)d_in[11];
    float* out = (float*)d_out;

    float* bufA = (float*)d_ws;
    float* bufB = bufA + (size_t)NPEAKS * HID * PEAK;   // 131 MB each

    proj_kernel<<<dim3(16, 4, NPEAKS), 256, 0, stream>>>(x, wproj, bproj, bufA);

    const int lens[DEPTHN + 1] = {1000, 996, 988, 972, 940, 876, 748, 492};
    float* bufs[2] = {bufA, bufB};
    for (int i = 0; i < DEPTHN; ++i) {
        int dil = 2 << i;                 // 2^(i+1)
        int in_len = lens[i], out_len = lens[i + 1];
        int t_tiles = (out_len + 63) / 64;
        dconv_kernel<<<dim3(t_tiles, 4, NPEAKS), 256, 0, stream>>>(
            bufs[i & 1], in_len, bufs[(i + 1) & 1], out_len, dil,
            wdil + (size_t)i * HID * HID * 3, bdil + (size_t)i * HID);
    }
    // final h is in bufB (len 492)
    atpm_kernel<<<NPEAKS, 256, 0, stream>>>(bufB, watpm, batpm, out);
    prof_kernel<<<dim3(2, NPEAKS), 256, 0, stream>>>(bufB, wprof, bprof, out + NPEAKS);
}

// Round 3
// 2697.690 us; speedup vs baseline: 2.8264x; 2.8264x over previous
//
#include <hip/hip_runtime.h>
#include <hip/hip_bf16.h>
#include <math.h>

#define HID 256
#define MOTIF 640
#define PEAK 1000
#define NPEAKS 128   // B * NUM_PEAKS
#define DEPTHN 7
#define PROFK 75
#define FINLEN 492
#define PROFLEN 418

typedef unsigned short u16;
typedef unsigned int u32;
typedef __bf16 bf16x8 __attribute__((ext_vector_type(8)));
typedef float f32x16 __attribute__((ext_vector_type(16)));

__device__ __forceinline__ float bflo(u32 u) { return __uint_as_float(u << 16); }
__device__ __forceinline__ float bfhi(u32 u) { return __uint_as_float(u & 0xffff0000u); }
__device__ __forceinline__ u16 f2bf(float f) {
    __hip_bfloat16 b = __float2bfloat16(f);   // RNE
    return *reinterpret_cast<u16*>(&b);
}
__device__ __forceinline__ u32 pk2(float a, float b) {
    return (u32)f2bf(a) | ((u32)f2bf(b) << 16);
}

// ---------------------------------------------------------------------------
// Weight repack (one dilated layer): w (HID,HID,3) fp32 -> bf16 [k*16+ci16][c][16]
// ---------------------------------------------------------------------------
__global__ __launch_bounds__(256) void conv_wdil1(const float* __restrict__ w,
                                                  u16* __restrict__ wf) {
    int i = blockIdx.x * 256 + threadIdx.x;          // < 3*256*256 = 196608
    int cil = i & 15; int j = i >> 4;
    int c = j & 255; j >>= 8;                        // j = k*16 + ci16
    int ci16 = j & 15; int k = j >> 4;
    wf[i] = f2bf(w[((size_t)c * HID + ci16 * 16 + cil) * 3 + k]);
}

// wproj (HID, MOTIF, 1) fp32 -> bf16 [m16][c][16]
__global__ __launch_bounds__(256) void conv_wproj(const float* __restrict__ w,
                                                  u16* __restrict__ wf) {
    int i = blockIdx.x * 256 + threadIdx.x;
    if (i >= MOTIF * HID) return;
    int ml = i & 15;
    int c = (i >> 4) & 255;
    int m16 = i >> 12;
    wf[i] = f2bf(w[(size_t)c * MOTIF + m16 * 16 + ml]);
}

// ---------------------------------------------------------------------------
// MFMA GEMM: dst[n][t][c] = act( sum_{k,ci} W[k][c][ci]*src[n][t+k*DIL][ci] + bias[c] )
//            (+ residual src[n][t+DIL][c] when RESID)
// Block 256 thr = 4 waves; tile 256c x 128t; wave (cg=w&1) 128c x (tg=w>>1) 64t.
// B staged once per block as union rows [t0, t0+127+(TAPS-1)*DIL], chunk-planar
// bf16 LDS; A-fragments read straight from L2-resident frag-ordered panel.
// ---------------------------------------------------------------------------
template<int TAPS, int KCI, int DIL, bool SRCBF, bool OUTBF, bool RESID>
__global__ __launch_bounds__(256) void mfma_gemm(
    const void* __restrict__ src, int in_len, int in_stride,
    const u16* __restrict__ wf, const float* __restrict__ bias,
    void* __restrict__ dst, int out_len)
{
    constexpr int R = 128 + (TAPS - 1) * DIL;        // union staged rows
    __shared__ __attribute__((aligned(16))) u16 Bs[4 * R * 8];
    const int tid = threadIdx.x;
    const int wave = tid >> 6, lane = tid & 63;
    const int col = lane & 31, half = lane >> 5;
    const int cg = wave & 1, tg = wave >> 1;
    const int t0 = blockIdx.x * 128;
    const int n  = blockIdx.y;

    const float* snf = (const float*)src + (size_t)n * in_len * in_stride;
    const u16*   snh = (const u16*)src + (size_t)n * in_len * in_stride;

    f32x16 acc[4][2];
    #pragma unroll
    for (int cs = 0; cs < 4; ++cs)
        #pragma unroll
        for (int ts = 0; ts < 2; ++ts)
            #pragma unroll
            for (int q = 0; q < 16; ++q) acc[cs][ts][q] = 0.f;

    for (int ci0 = 0; ci0 < KCI; ci0 += 32) {
        __syncthreads();
        for (int s = tid; s < R * 4; s += 256) {
            const int r = s >> 2, ch = s & 3;
            int g = t0 + r; if (g > in_len - 1) g = in_len - 1;
            u16* d = &Bs[(ch * R + r) * 8];
            if (SRCBF) {
                *(uint4*)d = *(const uint4*)(snh + (size_t)g * in_stride + ci0 + ch * 8);
            } else {
                const float* p = snf + (size_t)g * in_stride + ci0 + ch * 8;
                float4 a = *(const float4*)p;
                float4 b = *(const float4*)(p + 4);
                uint4 o;
                o.x = pk2(a.x, a.y); o.y = pk2(a.z, a.w);
                o.z = pk2(b.x, b.y); o.w = pk2(b.z, b.w);
                *(uint4*)d = o;
            }
        }
        __syncthreads();
        #pragma unroll
        for (int k = 0; k < TAPS; ++k) {
            #pragma unroll
            for (int s2 = 0; s2 < 2; ++s2) {
                const int ktile = k * (KCI / 16) + (ci0 >> 4) + s2;
                bf16x8 bf[2];
                #pragma unroll
                for (int ts = 0; ts < 2; ++ts)
                    bf[ts] = *reinterpret_cast<const bf16x8*>(
                        &Bs[((s2 * 2 + half) * R + tg * 64 + ts * 32 + col + k * DIL) * 8]);
                #pragma unroll
                for (int cs = 0; cs < 4; ++cs) {
                    const bf16x8 af = *reinterpret_cast<const bf16x8*>(
                        wf + ((size_t)(ktile * 256 + cg * 128 + cs * 32 + col) * 16 + half * 8));
                    acc[cs][0] = __builtin_amdgcn_mfma_f32_32x32x16_bf16(af, bf[0], acc[cs][0], 0, 0, 0);
                    acc[cs][1] = __builtin_amdgcn_mfma_f32_32x32x16_bf16(af, bf[1], acc[cs][1], 0, 0, 0);
                }
            }
        }
    }

    // Epilogue. C/D: c_local = (r&3) + 8*(r>>2) + 4*half, t = lane&31.
    #pragma unroll
    for (int ts = 0; ts < 2; ++ts) {
        const int t = t0 + tg * 64 + ts * 32 + col;
        if (t >= out_len) continue;
        const float* resf = snf + (size_t)(t + DIL) * in_stride;
        const u16*   resh = snh + (size_t)(t + DIL) * in_stride;
        float* of = (float*)dst + ((size_t)n * out_len + t) * HID;
        u16*   oh = (u16*)dst + ((size_t)n * out_len + t) * HID;
        #pragma unroll
        for (int cs = 0; cs < 4; ++cs) {
            #pragma unroll
            for (int g = 0; g < 4; ++g) {
                const int c = cg * 128 + cs * 32 + g * 8 + half * 4;
                float4 bv = *(const float4*)(bias + c);
                float v0 = acc[cs][ts][g * 4 + 0] + bv.x;
                float v1 = acc[cs][ts][g * 4 + 1] + bv.y;
                float v2 = acc[cs][ts][g * 4 + 2] + bv.z;
                float v3 = acc[cs][ts][g * 4 + 3] + bv.w;
                if (RESID) {
                    if (SRCBF) {
                        uint2 r = *(const uint2*)(resh + c);
                        v0 = fmaxf(v0, 0.f) + bflo(r.x);
                        v1 = fmaxf(v1, 0.f) + bfhi(r.x);
                        v2 = fmaxf(v2, 0.f) + bflo(r.y);
                        v3 = fmaxf(v3, 0.f) + bfhi(r.y);
                    } else {
                        float4 r = *(const float4*)(resf + c);
                        v0 = fmaxf(v0, 0.f) + r.x;
                        v1 = fmaxf(v1, 0.f) + r.y;
                        v2 = fmaxf(v2, 0.f) + r.z;
                        v3 = fmaxf(v3, 0.f) + r.w;
                    }
                }
                if (OUTBF) {
                    uint2 o; o.x = pk2(v0, v1); o.y = pk2(v2, v3);
                    *(uint2*)(oh + c) = o;
                } else {
                    *(float4*)(of + c) = make_float4(v0, v1, v2, v3);
                }
            }
        }
    }
}

// ---------------------------------------------------------------------------
// atpm head: out[n] = softplus( (sum_t h[n][t][.]/492) . w + b )   h fp32 [n][t][256]
// ---------------------------------------------------------------------------
__global__ __launch_bounds__(256) void atpm_kernel(
    const float* __restrict__ h, const float* __restrict__ watpm,
    const float* __restrict__ batpm, float* __restrict__ out)
{
    const int n = blockIdx.x, tid = threadIdx.x;
    const float* hn = h + (size_t)n * FINLEN * HID;
    const int cgi = (tid & 63) * 4, rg = tid >> 6;
    float a0 = 0, a1 = 0, a2 = 0, a3 = 0;
    for (int it = 0; it < FINLEN / 4; ++it) {
        const int t = it * 4 + rg;
        float4 v = *(const float4*)(hn + (size_t)t * HID + cgi);
        a0 += v.x; a1 += v.y; a2 += v.z; a3 += v.w;
    }
    float4 w = *(const float4*)(watpm + cgi);
    float s = a0 * w.x + a1 * w.y + a2 * w.z + a3 * w.w;
    #pragma unroll
    for (int off = 32; off; off >>= 1) s += __shfl_down(s, off, 64);
    __shared__ float red[4];
    if ((tid & 63) == 0) red[tid >> 6] = s;
    __syncthreads();
    if (tid == 0) {
        float tot = (red[0] + red[1] + red[2] + red[3]) / (float)FINLEN + batpm[0];
        out[n] = fmaxf(tot, 0.f) + log1pf(expf(-fabsf(tot)));
    }
}

// ---------------------------------------------------------------------------
// profile head: out[n][t] = softplus( sum_{ci,k} w[ci][k] h[n][t+k][ci] + b )
// hs transposed [ci][row] so the k-loop is stride-1 and conflict-free.
// grid (2, 128), block 256 (thread = output t)
// ---------------------------------------------------------------------------
__global__ __launch_bounds__(256) void prof_kernel(
    const float* __restrict__ h, const float* __restrict__ wprof,
    const float* __restrict__ bprof, float* __restrict__ out)
{
    __shared__ float hs[32][333];      // [ci][row], 330 rows used
    __shared__ float ws2[32][76];      // [ci][k]
    const int n = blockIdx.y, t0 = blockIdx.x * 256, tid = threadIdx.x;
    const float* hn = h + (size_t)n * FINLEN * HID;
    float acc = 0.f;
    for (int ci0 = 0; ci0 < HID; ci0 += 32) {
        __syncthreads();
        for (int s = tid; s < 330 * 8; s += 256) {
            const int row = s >> 3, ch = s & 7;
            int g = t0 + row; if (g > FINLEN - 1) g = FINLEN - 1;
            float4 v = *(const float4*)(hn + (size_t)g * HID + ci0 + ch * 4);
            hs[ch * 4 + 0][row] = v.x; hs[ch * 4 + 1][row] = v.y;
            hs[ch * 4 + 2][row] = v.z; hs[ch * 4 + 3][row] = v.w;
        }
        for (int s = tid; s < 32 * PROFK; s += 256) {
            const int ci = s / PROFK, k = s - ci * PROFK;
            ws2[ci][k] = wprof[(ci0 + ci) * PROFK + k];
        }
        __syncthreads();
        for (int ci = 0; ci < 32; ++ci) {
            const float* hr = &hs[ci][tid];
            const float* wr = &ws2[ci][0];
            #pragma unroll 5
            for (int k = 0; k < PROFK; ++k) acc += wr[k] * hr[k];
        }
    }
    const int t = t0 + tid;
    if (t < PROFLEN) {
        float v = acc + bprof[0];
        out[(size_t)n * PROFLEN + t] = fmaxf(v, 0.f) + log1pf(expf(-fabsf(v)));
    }
}

// ---------------------------------------------------------------------------
extern "C" void kernel_launch(void* const* d_in, const int* in_sizes, int n_in,
                              void* d_out, int out_size, void* d_ws, size_t ws_size,
                              hipStream_t stream) {
    const float* x     = (const float*)d_in[0];
    const float* wproj = (const float*)d_in[4];
    const float* bproj = (const float*)d_in[5];
    const float* wdil  = (const float*)d_in[6];
    const float* bdil  = (const float*)d_in[7];
    const float* wprof = (const float*)d_in[8];
    const float* bprof = (const float*)d_in[9];
    const float* watpm = (const float*)d_in[10];
    const float* batpm = (const float*)d_in[11];
    float* outAtpm = (float*)d_out;
    float* outProf = outAtpm + NPEAKS;

    // ws layout (total 260.77 MB, < proven-safe 262.14 MB):
    //   R2 @ 0          : 129,499,136 B  (h0 bf16 lives here, then h2,h4,h6 fp32)
    //   R1 @ 129499136  : 130,547,712 B  (h1,h3,h5,h7 fp32)
    //   wpf @ 260046848 : 327,680 B      (proj weights bf16 frag-ordered)
    //   wslot @ 260374528 : 393,216 B    (per-layer dilated weights, rotated)
    char* ws = (char*)d_ws;
    float* R2 = (float*)ws;
    float* R1 = (float*)(ws + 129499136);
    u16* h0    = (u16*)ws;
    u16* wpf   = (u16*)(ws + 260046848);
    u16* wslot = (u16*)(ws + 260374528);

    conv_wproj<<<(MOTIF * HID + 255) / 256, 256, 0, stream>>>(wproj, wpf);

    // projection: x fp32 (K=640) -> h0 bf16 [n][t][c]
    mfma_gemm<1, MOTIF, 0, false, true, false><<<dim3(8, NPEAKS), 256, 0, stream>>>(
        x, PEAK, MOTIF, wpf, bproj, h0, PEAK);

    const size_t WL = (size_t)3 * 16 * HID * 16;   // frag elements per layer
    #define LAYER(i, DIL, SRC, DST, SRCBF, INL, OUTL, TT)                              \
        conv_wdil1<<<768, 256, 0, stream>>>(wdil + (size_t)(i) * HID * HID * 3, wslot); \
        mfma_gemm<3, HID, DIL, SRCBF, false, true><<<dim3(TT, NPEAKS), 256, 0, stream>>>( \
            SRC, INL, HID, wslot, bdil + (size_t)(i) * HID, DST, OUTL);
    LAYER(0,   2, h0, R1, true,  1000, 996, 8)
    LAYER(1,   4, R1, R2, false,  996, 988, 8)
    LAYER(2,   8, R2, R1, false,  988, 972, 8)
    LAYER(3,  16, R1, R2, false,  972, 940, 8)
    LAYER(4,  32, R2, R1, false,  940, 876, 7)
    LAYER(5,  64, R1, R2, false,  876, 748, 6)
    LAYER(6, 128, R2, R1, false,  748, 492, 4)
    #undef LAYER

    // final h = R1 fp32, len 492
    atpm_kernel<<<NPEAKS, 256, 0, stream>>>(R1, watpm, batpm, outAtpm);
    prof_kernel<<<dim3(2, NPEAKS), 256, 0, stream>>>(R1, wprof, bprof, outProf);
}

// Round 5
// 2529.129 us; speedup vs baseline: 3.0147x; 1.0666x over previous
//
#include <hip/hip_runtime.h>
#include <hip/hip_bf16.h>
#include <math.h>

#define HID 256
#define MOTIF 640
#define PEAK 1000
#define NPEAKS 128   // B * NUM_PEAKS
#define DEPTHN 7
#define PROFK 75
#define FINLEN 492
#define PROFLEN 418

typedef unsigned short u16;
typedef unsigned int u32;
typedef __bf16 bf16x8 __attribute__((ext_vector_type(8)));
typedef float f32x16 __attribute__((ext_vector_type(16)));

__device__ __forceinline__ float bflo(u32 u) { return __uint_as_float(u << 16); }
__device__ __forceinline__ float bfhi(u32 u) { return __uint_as_float(u & 0xffff0000u); }
__device__ __forceinline__ u16 f2bf(float f) {
    __hip_bfloat16 b = __float2bfloat16(f);   // RNE
    return *reinterpret_cast<u16*>(&b);
}
__device__ __forceinline__ u32 pk2(float a, float b) {
    return (u32)f2bf(a) | ((u32)f2bf(b) << 16);
}

// ---------------------------------------------------------------------------
// Weight repack (one dilated layer): w (HID,HID,3) fp32 -> bf16 [k*16+ci16][c][16]
// Also zeroes the 128-float atpm partial buffer when zp != nullptr.
// ---------------------------------------------------------------------------
__global__ __launch_bounds__(256) void conv_wdil1(const float* __restrict__ w,
                                                  u16* __restrict__ wf,
                                                  float* zp) {
    int i = blockIdx.x * 256 + threadIdx.x;          // grid covers 3*256*256 exactly
    if (zp && i < NPEAKS) zp[i] = 0.f;
    int cil = i & 15; int j = i >> 4;
    int c = j & 255; j >>= 8;                        // j = k*16 + ci16
    int ci16 = j & 15; int k = j >> 4;
    wf[i] = f2bf(w[((size_t)c * HID + ci16 * 16 + cil) * 3 + k]);
}

// wproj (HID, MOTIF, 1) fp32 -> bf16 [m16][c][16]
__global__ __launch_bounds__(256) void conv_wproj(const float* __restrict__ w,
                                                  u16* __restrict__ wf) {
    int i = blockIdx.x * 256 + threadIdx.x;
    if (i >= MOTIF * HID) return;
    int ml = i & 15;
    int c = (i >> 4) & 255;
    int m16 = i >> 12;
    wf[i] = f2bf(w[(size_t)c * MOTIF + m16 * 16 + ml]);
}

// ---------------------------------------------------------------------------
// MFMA GEMM: dst[n][t][c] = act( sum_{k,ci} W[k][c][ci]*src[n][t+k*DIL][ci] + bias[c] )
//            (+ residual src[n][t+DIL][c] when RESID; + fused atpm partial when ATPM)
// Block 256 thr = 4 waves; tile 256c x 128t; K staged in 64-ci chunks.
// ---------------------------------------------------------------------------
template<int TAPS, int KCI, int DIL, bool SRCBF, bool OUTBF, bool RESID, bool ATPM>
__global__ __launch_bounds__(256) void mfma_gemm(
    const void* __restrict__ src, int in_len, int in_stride,
    const u16* __restrict__ wf, const float* __restrict__ bias,
    void* __restrict__ dst, int out_len,
    const float* __restrict__ watpm, float* part)
{
    constexpr int R = 128 + (TAPS - 1) * DIL;        // union staged rows
    __shared__ __attribute__((aligned(16))) u16 Bs[8 * R * 8];   // 8 ci-planes x R x 8ci
    __shared__ float aw[4];
    const int tid = threadIdx.x;
    const int wave = tid >> 6, lane = tid & 63;
    const int col = lane & 31, half = lane >> 5;
    const int cg = wave & 1, tg = wave >> 1;
    const int t0 = blockIdx.x * 128;
    const int n  = blockIdx.y;

    const float* snf = (const float*)src + (size_t)n * in_len * in_stride;
    const u16*   snh = (const u16*)src + (size_t)n * in_len * in_stride;

    f32x16 acc[4][2];
    #pragma unroll
    for (int cs = 0; cs < 4; ++cs)
        #pragma unroll
        for (int ts = 0; ts < 2; ++ts)
            #pragma unroll
            for (int q = 0; q < 16; ++q) acc[cs][ts][q] = 0.f;

    for (int ci0 = 0; ci0 < KCI; ci0 += 64) {
        __syncthreads();
        for (int s = tid; s < R * 8; s += 256) {
            const int r = s >> 3, ch = s & 7;
            int g = t0 + r; if (g > in_len - 1) g = in_len - 1;
            u16* d = &Bs[(ch * R + r) * 8];
            if (SRCBF) {
                *(uint4*)d = *(const uint4*)(snh + (size_t)g * in_stride + ci0 + ch * 8);
            } else {
                const float* p = snf + (size_t)g * in_stride + ci0 + ch * 8;
                float4 a = *(const float4*)p;
                float4 b = *(const float4*)(p + 4);
                uint4 o;
                o.x = pk2(a.x, a.y); o.y = pk2(a.z, a.w);
                o.z = pk2(b.x, b.y); o.w = pk2(b.z, b.w);
                *(uint4*)d = o;
            }
        }
        __syncthreads();
        #pragma unroll
        for (int k = 0; k < TAPS; ++k) {
            #pragma unroll
            for (int s2 = 0; s2 < 4; ++s2) {
                const int ktile = k * (KCI / 16) + (ci0 >> 4) + s2;
                bf16x8 bf[2];
                #pragma unroll
                for (int ts = 0; ts < 2; ++ts)
                    bf[ts] = *reinterpret_cast<const bf16x8*>(
                        &Bs[((s2 * 2 + half) * R + tg * 64 + ts * 32 + col + k * DIL) * 8]);
                #pragma unroll
                for (int cs = 0; cs < 4; ++cs) {
                    const bf16x8 af = *reinterpret_cast<const bf16x8*>(
                        wf + ((size_t)(ktile * 256 + cg * 128 + cs * 32 + col) * 16 + half * 8));
                    acc[cs][0] = __builtin_amdgcn_mfma_f32_32x32x16_bf16(af, bf[0], acc[cs][0], 0, 0, 0);
                    acc[cs][1] = __builtin_amdgcn_mfma_f32_32x32x16_bf16(af, bf[1], acc[cs][1], 0, 0, 0);
                }
            }
        }
    }

    // Epilogue. C/D: c_local = (r&3) + 8*(r>>2) + 4*half, t = lane&31.
    float apart = 0.f;
    #pragma unroll
    for (int ts = 0; ts < 2; ++ts) {
        const int t = t0 + tg * 64 + ts * 32 + col;
        if (t >= out_len) continue;
        const float* resf = snf + (size_t)(t + DIL) * in_stride;
        const u16*   resh = snh + (size_t)(t + DIL) * in_stride;
        float* of = (float*)dst + ((size_t)n * out_len + t) * HID;
        u16*   oh = (u16*)dst + ((size_t)n * out_len + t) * HID;
        #pragma unroll
        for (int cs = 0; cs < 4; ++cs) {
            #pragma unroll
            for (int g = 0; g < 4; ++g) {
                const int c = cg * 128 + cs * 32 + g * 8 + half * 4;
                float4 bv = *(const float4*)(bias + c);
                float v0 = acc[cs][ts][g * 4 + 0] + bv.x;
                float v1 = acc[cs][ts][g * 4 + 1] + bv.y;
                float v2 = acc[cs][ts][g * 4 + 2] + bv.z;
                float v3 = acc[cs][ts][g * 4 + 3] + bv.w;
                if (RESID) {
                    if (SRCBF) {
                        uint2 r = *(const uint2*)(resh + c);
                        v0 = fmaxf(v0, 0.f) + bflo(r.x);
                        v1 = fmaxf(v1, 0.f) + bfhi(r.x);
                        v2 = fmaxf(v2, 0.f) + bflo(r.y);
                        v3 = fmaxf(v3, 0.f) + bfhi(r.y);
                    } else {
                        float4 r = *(const float4*)(resf + c);
                        v0 = fmaxf(v0, 0.f) + r.x;
                        v1 = fmaxf(v1, 0.f) + r.y;
                        v2 = fmaxf(v2, 0.f) + r.z;
                        v3 = fmaxf(v3, 0.f) + r.w;
                    }
                }
                if (ATPM) {
                    float4 wv = *(const float4*)(watpm + c);
                    apart += v0 * wv.x + v1 * wv.y + v2 * wv.z + v3 * wv.w;
                }
                if (OUTBF) {
                    uint2 o; o.x = pk2(v0, v1); o.y = pk2(v2, v3);
                    *(uint2*)(oh + c) = o;
                } else {
                    *(float4*)(of + c) = make_float4(v0, v1, v2, v3);
                }
            }
        }
    }
    if (ATPM) {
        #pragma unroll
        for (int off = 32; off; off >>= 1) apart += __shfl_down(apart, off, 64);
        if (lane == 0) aw[wave] = apart;
        __syncthreads();
        if (tid == 0) atomicAdd(part + n, aw[0] + aw[1] + aw[2] + aw[3]);
    }
}

// ---------------------------------------------------------------------------
// atpm finalize: out[n] = softplus(part[n]/492 + b)
// ---------------------------------------------------------------------------
__global__ void atpm_fin(const float* __restrict__ part,
                         const float* __restrict__ batpm, float* __restrict__ out) {
    int i = threadIdx.x;   // 128
    float tot = part[i] / (float)FINLEN + batpm[0];
    out[i] = fmaxf(tot, 0.f) + log1pf(expf(-fabsf(tot)));
}

// ---------------------------------------------------------------------------
// profile head, sliding-window: out[n][t] = softplus( sum_{ci,k} w[ci][k] h[n][t+k][ci] + b )
// Block covers 128 t; thread = (ts 0..31, cig 0..7), owns T=4 t's and 8-ci subranges.
// h staged transposed [ci][204] fp32; h-reads are ds_read_b128, conflict-free.
// Weights in per-thread register array (zero-padded), loaded from L2-resident global.
// grid (4, 128), block 256.
// ---------------------------------------------------------------------------
__global__ __launch_bounds__(256) void prof_kernel(
    const float* __restrict__ h, const float* __restrict__ wprof,
    const float* __restrict__ bprof, float* __restrict__ out)
{
    __shared__ __attribute__((aligned(16))) float hs[64 * 204];  // 52.2 KB
    __shared__ float red[128 * 8];                               // 4 KB
    const int tid = threadIdx.x;
    const int wave = tid >> 6, lane = tid & 63;
    const int ts = lane & 31, hw = lane >> 5;
    const int cig = wave * 2 + hw;           // 0..7
    const int n = blockIdx.y, t0 = blockIdx.x * 128;
    const float* hn = h + (size_t)n * FINLEN * HID;
    float acc[4] = {0.f, 0.f, 0.f, 0.f};

    for (int ci0 = 0; ci0 < HID; ci0 += 64) {
        __syncthreads();
        {   // stage rows [t0, t0+203] (clamped) for ci-window, transposed
            const int ci = tid & 63, rg = tid >> 6;
            for (int base = 0; base < 204; base += 16) {
                const int r0 = base + rg * 4;
                if (r0 >= 204) continue;
                float4 v;
                float* vp = (float*)&v;
                #pragma unroll
                for (int j = 0; j < 4; ++j) {
                    int g = t0 + r0 + j; if (g > FINLEN - 1) g = FINLEN - 1;
                    vp[j] = hn[(size_t)g * HID + ci0 + ci];
                }
                *(float4*)&hs[ci * 204 + r0] = v;
            }
        }
        __syncthreads();
        for (int ci = 0; ci < 8; ++ci) {
            const int cia = cig * 8 + ci;
            const float4* hrow = (const float4*)&hs[cia * 204];
            const float* wrow = wprof + (size_t)(ci0 + cia) * PROFK;
            float wqf[84];
            #pragma unroll
            for (int q = 0; q < 3; ++q) wqf[q] = 0.f;
            #pragma unroll
            for (int q = 78; q < 84; ++q) wqf[q] = 0.f;
            #pragma unroll
            for (int k = 0; k < PROFK; ++k) wqf[k + 3] = wrow[k];
            #pragma unroll
            for (int m = 0; m < 20; ++m) {
                float4 h4 = hrow[ts + m];
                const float* hp = (const float*)&h4;
                #pragma unroll
                for (int j = 0; j < 4; ++j) {
                    #pragma unroll
                    for (int a = 0; a < 4; ++a) {
                        acc[a] += wqf[4 * m + j - a + 3] * hp[j];
                    }
                }
            }
        }
    }
    #pragma unroll
    for (int a = 0; a < 4; ++a) red[(ts * 4 + a) * 8 + cig] = acc[a];
    __syncthreads();
    if (tid < 128) {
        float s = 0.f;
        #pragma unroll
        for (int c8 = 0; c8 < 8; ++c8) s += red[tid * 8 + c8];
        const int t = t0 + tid;
        if (t < PROFLEN) {
            float v = s + bprof[0];
            out[(size_t)n * PROFLEN + t] = fmaxf(v, 0.f) + log1pf(expf(-fabsf(v)));
        }
    }
}

// ---------------------------------------------------------------------------
extern "C" void kernel_launch(void* const* d_in, const int* in_sizes, int n_in,
                              void* d_out, int out_size, void* d_ws, size_t ws_size,
                              hipStream_t stream) {
    const float* x     = (const float*)d_in[0];
    const float* wproj = (const float*)d_in[4];
    const float* bproj = (const float*)d_in[5];
    const float* wdil  = (const float*)d_in[6];
    const float* bdil  = (const float*)d_in[7];
    const float* wprof = (const float*)d_in[8];
    const float* bprof = (const float*)d_in[9];
    const float* watpm = (const float*)d_in[10];
    const float* batpm = (const float*)d_in[11];
    float* outAtpm = (float*)d_out;
    float* outProf = outAtpm + NPEAKS;

    // ws layout (total ~260.77 MB):
    //   R2 @ 0          : h0 bf16, then h2,h4,h6 fp32
    //   R1 @ 129499136  : h1,h3,h5,h7 fp32
    //   wpf @ 260046848 : proj weights bf16 frag-ordered
    //   wslot @ 260374528 : per-layer dilated weights (rotated)
    //   part @ 260767744 : 128-float atpm partials
    char* ws = (char*)d_ws;
    float* R2 = (float*)ws;
    float* R1 = (float*)(ws + 129499136);
    u16* h0    = (u16*)ws;
    u16* wpf   = (u16*)(ws + 260046848);
    u16* wslot = (u16*)(ws + 260374528);
    float* part = (float*)(ws + 260767744);

    conv_wproj<<<(MOTIF * HID + 255) / 256, 256, 0, stream>>>(wproj, wpf);

    // projection: x fp32 (K=640) -> h0 bf16 [n][t][c]
    mfma_gemm<1, MOTIF, 0, false, true, false, false><<<dim3(8, NPEAKS), 256, 0, stream>>>(
        x, PEAK, MOTIF, wpf, bproj, h0, PEAK, nullptr, nullptr);

    #define LAYER(i, DIL, SRC, DST, SRCBF, INL, OUTL, TT)                                   \
        conv_wdil1<<<768, 256, 0, stream>>>(wdil + (size_t)(i) * HID * HID * 3, wslot,      \
                                            nullptr);                                       \
        mfma_gemm<3, HID, DIL, SRCBF, false, true, false><<<dim3(TT, NPEAKS), 256, 0, stream>>>( \
            SRC, INL, HID, wslot, bdil + (size_t)(i) * HID, DST, OUTL, nullptr, nullptr);
    LAYER(0,   2, h0, R1, true,  1000, 996, 8)
    LAYER(1,   4, R1, R2, false,  996, 988, 8)
    LAYER(2,   8, R2, R1, false,  988, 972, 8)
    LAYER(3,  16, R1, R2, false,  972, 940, 8)
    LAYER(4,  32, R2, R1, false,  940, 876, 7)
    LAYER(5,  64, R1, R2, false,  876, 748, 6)
    #undef LAYER
    // layer 6 with fused atpm partial accumulation (part zeroed in its repack)
    conv_wdil1<<<768, 256, 0, stream>>>(wdil + (size_t)6 * HID * HID * 3, wslot, part);
    mfma_gemm<3, HID, 128, false, false, true, true><<<dim3(4, NPEAKS), 256, 0, stream>>>(
        R2, 748, HID, wslot, bdil + (size_t)6 * HID, R1, 492, watpm, part);

    atpm_fin<<<1, 128, 0, stream>>>(part, batpm, outAtpm);
    prof_kernel<<<dim3(4, NPEAKS), 256, 0, stream>>>(R1, wprof, bprof, outProf);
}

// Round 6
// 1256.571 us; speedup vs baseline: 6.0679x; 2.0127x over previous
//
#include <hip/hip_runtime.h>
#include <hip/hip_bf16.h>
#include <math.h>

#define HID 256
#define MOTIF 640
#define PEAK 1000
#define NPEAKS 128   // B * NUM_PEAKS
#define DEPTHN 7
#define PROFK 75
#define FINLEN 492
#define PROFLEN 418

typedef unsigned short u16;
typedef unsigned int u32;
typedef _Float16 f16x8 __attribute__((ext_vector_type(8)));
typedef float f32x16 __attribute__((ext_vector_type(16)));

__device__ __forceinline__ u16 f2h(float f) {
    _Float16 h = (_Float16)f; u16 b; __builtin_memcpy(&b, &h, 2); return b;
}
__device__ __forceinline__ float h2f(u16 b) {
    _Float16 h; __builtin_memcpy(&h, &b, 2); return (float)h;
}
__device__ __forceinline__ float hlo(u32 u) { return h2f((u16)(u & 0xffff)); }
__device__ __forceinline__ float hhi(u32 u) { return h2f((u16)(u >> 16)); }
__device__ __forceinline__ u32 pk2h(float a, float b) {
    return (u32)f2h(a) | ((u32)f2h(b) << 16);
}

// ---------------------------------------------------------------------------
// Weight repack (one dilated layer): w (HID,HID,3) fp32 -> fp16 [k*16+ci16][c][16]
// Also zeroes the 128-float atpm partial buffer when zp != nullptr.
// ---------------------------------------------------------------------------
__global__ __launch_bounds__(256) void conv_wdil1(const float* __restrict__ w,
                                                  u16* __restrict__ wf,
                                                  float* zp) {
    int i = blockIdx.x * 256 + threadIdx.x;          // grid covers 3*256*256 exactly
    if (zp && i < NPEAKS) zp[i] = 0.f;
    int cil = i & 15; int j = i >> 4;
    int c = j & 255; j >>= 8;                        // j = k*16 + ci16
    int ci16 = j & 15; int k = j >> 4;
    wf[i] = f2h(w[((size_t)c * HID + ci16 * 16 + cil) * 3 + k]);
}

// wproj (HID, MOTIF, 1) fp32 -> fp16 [m16][c][16]
__global__ __launch_bounds__(256) void conv_wproj(const float* __restrict__ w,
                                                  u16* __restrict__ wf) {
    int i = blockIdx.x * 256 + threadIdx.x;
    if (i >= MOTIF * HID) return;
    int ml = i & 15;
    int c = (i >> 4) & 255;
    int m16 = i >> 12;
    wf[i] = f2h(w[(size_t)c * MOTIF + m16 * 16 + ml]);
}

// ---------------------------------------------------------------------------
// MFMA GEMM: dst[n][t][c] = act( sum_{k,ci} W[k][c][ci]*src[n][t+k*DIL][ci] + bias[c] )
//            (+ residual src[n][t+DIL][c] when RESID; + fused atpm partial when ATPM)
// Block 256 thr = 4 waves; tile 128c x 128t (wave 64c x 64t, acc[2][2]).
// K staged in 64-ci chunks, chunk-planar fp16 LDS; A-frags from L2-resident panel.
// __launch_bounds__(256,3): >=3 waves/SIMD so >=3 blocks/CU overlap stage/compute.
// ---------------------------------------------------------------------------
template<int TAPS, int KCI, int DIL, bool SRCF32, bool RESID, bool ATPM>
__global__ __launch_bounds__(256, 3) void mfma_gemm(
    const void* __restrict__ src, int in_len, int in_stride,
    const u16* __restrict__ wf, const float* __restrict__ bias,
    u16* __restrict__ dst, int out_len,
    const float* __restrict__ watpm, float* part)
{
    constexpr int R = 128 + (TAPS - 1) * DIL;        // union staged rows
    __shared__ __attribute__((aligned(16))) u16 Bs[8 * R * 8];   // 8 ci-planes x R x 8ci
    __shared__ float aw[4];
    const int tid = threadIdx.x;
    const int wave = tid >> 6, lane = tid & 63;
    const int col = lane & 31, half = lane >> 5;
    const int cg = wave & 1, tg = wave >> 1;
    const int t0 = blockIdx.x * 128;
    const int c0 = blockIdx.y * 128;
    const int n  = blockIdx.z;

    const float* snf = (const float*)src + (size_t)n * in_len * in_stride;
    const u16*   snh = (const u16*)src + (size_t)n * in_len * in_stride;

    f32x16 acc[2][2];
    #pragma unroll
    for (int cs = 0; cs < 2; ++cs)
        #pragma unroll
        for (int ts = 0; ts < 2; ++ts)
            #pragma unroll
            for (int q = 0; q < 16; ++q) acc[cs][ts][q] = 0.f;

    for (int ci0 = 0; ci0 < KCI; ci0 += 64) {
        __syncthreads();
        for (int s = tid; s < R * 8; s += 256) {
            const int r = s >> 3, ch = s & 7;
            int g = t0 + r; if (g > in_len - 1) g = in_len - 1;
            u16* d = &Bs[(ch * R + r) * 8];
            if (SRCF32) {
                const float* p = snf + (size_t)g * in_stride + ci0 + ch * 8;
                float4 a = *(const float4*)p;
                float4 b = *(const float4*)(p + 4);
                uint4 o;
                o.x = pk2h(a.x, a.y); o.y = pk2h(a.z, a.w);
                o.z = pk2h(b.x, b.y); o.w = pk2h(b.z, b.w);
                *(uint4*)d = o;
            } else {
                *(uint4*)d = *(const uint4*)(snh + (size_t)g * in_stride + ci0 + ch * 8);
            }
        }
        __syncthreads();
        #pragma unroll
        for (int k = 0; k < TAPS; ++k) {
            #pragma unroll
            for (int s2 = 0; s2 < 4; ++s2) {
                const int ktile = k * (KCI / 16) + (ci0 >> 4) + s2;
                f16x8 bfv[2];
                #pragma unroll
                for (int ts = 0; ts < 2; ++ts)
                    bfv[ts] = *reinterpret_cast<const f16x8*>(
                        &Bs[((s2 * 2 + half) * R + tg * 64 + ts * 32 + col + k * DIL) * 8]);
                #pragma unroll
                for (int cs = 0; cs < 2; ++cs) {
                    const f16x8 af = *reinterpret_cast<const f16x8*>(
                        wf + ((size_t)(ktile * 256 + c0 + cg * 64 + cs * 32 + col) * 16 + half * 8));
                    acc[cs][0] = __builtin_amdgcn_mfma_f32_32x32x16_f16(af, bfv[0], acc[cs][0], 0, 0, 0);
                    acc[cs][1] = __builtin_amdgcn_mfma_f32_32x32x16_f16(af, bfv[1], acc[cs][1], 0, 0, 0);
                }
            }
        }
    }

    // Epilogue. C/D: c_local = (r&3) + 8*(r>>2) + 4*half, t = lane&31.
    float apart = 0.f;
    #pragma unroll
    for (int ts = 0; ts < 2; ++ts) {
        const int t = t0 + tg * 64 + ts * 32 + col;
        if (t >= out_len) continue;
        const float* resf = snf + (size_t)(t + DIL) * in_stride;
        const u16*   resh = snh + (size_t)(t + DIL) * in_stride;
        u16* oh = dst + ((size_t)n * out_len + t) * HID;
        #pragma unroll
        for (int cs = 0; cs < 2; ++cs) {
            #pragma unroll
            for (int g = 0; g < 4; ++g) {
                const int c = c0 + cg * 64 + cs * 32 + g * 8 + half * 4;
                float4 bv = *(const float4*)(bias + c);
                float v0 = acc[cs][ts][g * 4 + 0] + bv.x;
                float v1 = acc[cs][ts][g * 4 + 1] + bv.y;
                float v2 = acc[cs][ts][g * 4 + 2] + bv.z;
                float v3 = acc[cs][ts][g * 4 + 3] + bv.w;
                if (RESID) {
                    if (SRCF32) {
                        float4 r = *(const float4*)(resf + c);
                        v0 = fmaxf(v0, 0.f) + r.x;
                        v1 = fmaxf(v1, 0.f) + r.y;
                        v2 = fmaxf(v2, 0.f) + r.z;
                        v3 = fmaxf(v3, 0.f) + r.w;
                    } else {
                        uint2 r = *(const uint2*)(resh + c);
                        v0 = fmaxf(v0, 0.f) + hlo(r.x);
                        v1 = fmaxf(v1, 0.f) + hhi(r.x);
                        v2 = fmaxf(v2, 0.f) + hlo(r.y);
                        v3 = fmaxf(v3, 0.f) + hhi(r.y);
                    }
                }
                if (ATPM) {
                    float4 wv = *(const float4*)(watpm + c);
                    apart += v0 * wv.x + v1 * wv.y + v2 * wv.z + v3 * wv.w;
                }
                uint2 o; o.x = pk2h(v0, v1); o.y = pk2h(v2, v3);
                *(uint2*)(oh + c) = o;
            }
        }
    }
    if (ATPM) {
        #pragma unroll
        for (int off = 32; off; off >>= 1) apart += __shfl_down(apart, off, 64);
        if (lane == 0) aw[wave] = apart;
        __syncthreads();
        if (tid == 0) atomicAdd(part + n, aw[0] + aw[1] + aw[2] + aw[3]);
    }
}

// ---------------------------------------------------------------------------
// atpm finalize: out[n] = softplus(part[n]/492 + b)
// ---------------------------------------------------------------------------
__global__ void atpm_fin(const float* __restrict__ part,
                         const float* __restrict__ batpm, float* __restrict__ out) {
    int i = threadIdx.x;   // 128
    float tot = part[i] / (float)FINLEN + batpm[0];
    out[i] = fmaxf(tot, 0.f) + log1pf(expf(-fabsf(tot)));
}

// ---------------------------------------------------------------------------
// profile head, sliding-window: out[n][t] = softplus( sum_{ci,k} w[ci][k] h[n][t+k][ci] + b )
// h is fp16 [n][t][256]. Block covers 128 t; thread owns 4 t's x 8-ci subrange.
// grid (4, 128), block 256.
// ---------------------------------------------------------------------------
__global__ __launch_bounds__(256) void prof_kernel(
    const u16* __restrict__ h, const float* __restrict__ wprof,
    const float* __restrict__ bprof, float* __restrict__ out)
{
    __shared__ __attribute__((aligned(16))) float hs[64 * 204];  // 52.2 KB
    __shared__ float red[128 * 8];                               // 4 KB
    const int tid = threadIdx.x;
    const int wave = tid >> 6, lane = tid & 63;
    const int ts = lane & 31, hw = lane >> 5;
    const int cig = wave * 2 + hw;           // 0..7
    const int n = blockIdx.y, t0 = blockIdx.x * 128;
    const u16* hn = h + (size_t)n * FINLEN * HID;
    float acc[4] = {0.f, 0.f, 0.f, 0.f};

    for (int ci0 = 0; ci0 < HID; ci0 += 64) {
        __syncthreads();
        {   // stage rows [t0, t0+203] (clamped) for ci-window, transposed
            const int ci = tid & 63, rg = tid >> 6;
            for (int base = 0; base < 204; base += 16) {
                const int r0 = base + rg * 4;
                if (r0 >= 204) continue;
                float4 v;
                float* vp = (float*)&v;
                #pragma unroll
                for (int j = 0; j < 4; ++j) {
                    int g = t0 + r0 + j; if (g > FINLEN - 1) g = FINLEN - 1;
                    vp[j] = h2f(hn[(size_t)g * HID + ci0 + ci]);
                }
                *(float4*)&hs[ci * 204 + r0] = v;
            }
        }
        __syncthreads();
        for (int ci = 0; ci < 8; ++ci) {
            const int cia = cig * 8 + ci;
            const float4* hrow = (const float4*)&hs[cia * 204];
            const float* wrow = wprof + (size_t)(ci0 + cia) * PROFK;
            float wqf[84];
            #pragma unroll
            for (int q = 0; q < 3; ++q) wqf[q] = 0.f;
            #pragma unroll
            for (int q = 78; q < 84; ++q) wqf[q] = 0.f;
            #pragma unroll
            for (int k = 0; k < PROFK; ++k) wqf[k + 3] = wrow[k];
            #pragma unroll
            for (int m = 0; m < 20; ++m) {
                float4 h4 = hrow[ts + m];
                const float* hp = (const float*)&h4;
                #pragma unroll
                for (int j = 0; j < 4; ++j) {
                    #pragma unroll
                    for (int a = 0; a < 4; ++a) {
                        acc[a] += wqf[4 * m + j - a + 3] * hp[j];
                    }
                }
            }
        }
    }
    #pragma unroll
    for (int a = 0; a < 4; ++a) red[(ts * 4 + a) * 8 + cig] = acc[a];
    __syncthreads();
    if (tid < 128) {
        float s = 0.f;
        #pragma unroll
        for (int c8 = 0; c8 < 8; ++c8) s += red[tid * 8 + c8];
        const int t = t0 + tid;
        if (t < PROFLEN) {
            float v = s + bprof[0];
            out[(size_t)n * PROFLEN + t] = fmaxf(v, 0.f) + log1pf(expf(-fabsf(v)));
        }
    }
}

// ---------------------------------------------------------------------------
extern "C" void kernel_launch(void* const* d_in, const int* in_sizes, int n_in,
                              void* d_out, int out_size, void* d_ws, size_t ws_size,
                              hipStream_t stream) {
    const float* x     = (const float*)d_in[0];
    const float* wproj = (const float*)d_in[4];
    const float* bproj = (const float*)d_in[5];
    const float* wdil  = (const float*)d_in[6];
    const float* bdil  = (const float*)d_in[7];
    const float* wprof = (const float*)d_in[8];
    const float* bprof = (const float*)d_in[9];
    const float* watpm = (const float*)d_in[10];
    const float* batpm = (const float*)d_in[11];
    float* outAtpm = (float*)d_out;
    float* outProf = outAtpm + NPEAKS;

    // ws layout (~131.8 MB of the >=262 MB workspace), all fp16 activations:
    //   hA @ 0          : 65,536,000 B
    //   hB @ 65536000   : 65,536,000 B
    //   wpf @ 131072000 : 327,680 B (proj weights fp16 frag-ordered)
    //   wslot @ 131399680 : 393,216 B (per-layer dilated weights, rotated)
    //   part @ 131792896 : 512 B (atpm partials)
    char* ws = (char*)d_ws;
    u16* hA    = (u16*)ws;
    u16* hB    = (u16*)(ws + 65536000);
    u16* wpf   = (u16*)(ws + 131072000);
    u16* wslot = (u16*)(ws + 131399680);
    float* part = (float*)(ws + 131792896);

    conv_wproj<<<(MOTIF * HID + 255) / 256, 256, 0, stream>>>(wproj, wpf);

    // projection: x fp32 (K=640) -> hA fp16 [n][t][c]
    mfma_gemm<1, MOTIF, 0, true, false, false><<<dim3(8, 2, NPEAKS), 256, 0, stream>>>(
        x, PEAK, MOTIF, wpf, bproj, hA, PEAK, nullptr, nullptr);

    #define LAYER(i, DIL, SRC, DST, INL, OUTL, TT)                                          \
        conv_wdil1<<<768, 256, 0, stream>>>(wdil + (size_t)(i) * HID * HID * 3, wslot,      \
                                            nullptr);                                       \
        mfma_gemm<3, HID, DIL, false, true, false><<<dim3(TT, 2, NPEAKS), 256, 0, stream>>>( \
            SRC, INL, HID, wslot, bdil + (size_t)(i) * HID, DST, OUTL, nullptr, nullptr);
    LAYER(0,   2, hA, hB, 1000, 996, 8)
    LAYER(1,   4, hB, hA,  996, 988, 8)
    LAYER(2,   8, hA, hB,  988, 972, 8)
    LAYER(3,  16, hB, hA,  972, 940, 8)
    LAYER(4,  32, hA, hB,  940, 876, 7)
    LAYER(5,  64, hB, hA,  876, 748, 6)
    #undef LAYER
    // layer 6 with fused atpm partial accumulation (part zeroed in its repack)
    conv_wdil1<<<768, 256, 0, stream>>>(wdil + (size_t)6 * HID * HID * 3, wslot, part);
    mfma_gemm<3, HID, 128, false, true, true><<<dim3(4, 2, NPEAKS), 256, 0, stream>>>(
        hA, 748, HID, wslot, bdil + (size_t)6 * HID, hB, 492, watpm, part);

    atpm_fin<<<1, 128, 0, stream>>>(part, batpm, outAtpm);
    prof_kernel<<<dim3(4, NPEAKS), 256, 0, stream>>>(hB, wprof, bprof, outProf);
}